// Round 1
// baseline (424.398 us; speedup 1.0000x reference)
//
#include <hip/hip_runtime.h>
#include <math.h>

// VolumeCarver: per-ray volume rendering weight sum.
// R = 262144 rays, L = 128 samples/ray.
// One wave (64 lanes) per ray; each lane handles elements 2l and 2l+1.
// weight[i] = alpha[i] * prod_{j=1..i} trans_raw[j]   (note: includes j=i, excludes j=0)
// out[ray]  = sum_i weight[i]

#define NRAYS 262144
#define LEN   128
#define MAXD  1e10f
#define EPSW  1e-10f

__global__ __launch_bounds__(256) void vc_kernel(
    const float* __restrict__ t_stops,   // [R, L]
    const int*   __restrict__ leaves,    // [R, L] (int32 per harness contract)
    const float* __restrict__ logits,    // [NUM_LEAVES]
    float*       __restrict__ out)       // [R]
{
    const int lane = threadIdx.x & 63;
    const int wave = threadIdx.x >> 6;            // 4 waves per 256-thread block
    const int ray  = blockIdx.x * 4 + wave;

    const long long base = (long long)ray * LEN + 2 * lane;

    // Coalesced 8B/lane loads: wave covers the ray's contiguous 512B row.
    float2 t2 = *(const float2*)(t_stops + base);
    int2   lv = *(const int2*)(leaves + base);

    // delta[2l]   = t[2l+1] - t[2l]
    // delta[2l+1] = t[2l+2] - t[2l+1]   (next lane's t2.x), last element -> MAXD
    float t_next = __shfl_down(t2.x, 1);
    float d0 = t2.y - t2.x;
    float d1 = (lane == 63) ? MAXD : (t_next - t2.y);

    // Gather logits (random; table is 4MB -> L2-resident), sigmoid.
    float lg0 = logits[lv.x];
    float lg1 = logits[lv.y];
    float op0 = 1.0f / (1.0f + expf(-lg0));
    float op1 = 1.0f / (1.0f + expf(-lg1));

    // alpha = 1 - exp(-op*delta), computed via expm1 for small-argument accuracy.
    float a0 = -expm1f(-op0 * d0);
    float a1 = -expm1f(-op1 * d1);

    // trans_raw = min(1, 1 - alpha + eps); element 0 is excluded from the product.
    float tr0 = fminf(1.0f, 1.0f - a0 + EPSW);
    float tr1 = fminf(1.0f, 1.0f - a1 + EPSW);
    if (lane == 0) tr0 = 1.0f;                    // tr'[0] = 1

    float p01 = tr0 * tr1;                        // product of this lane's pair

    // Inclusive product scan of p01 across the 64 lanes (Hillis-Steele).
    float scan = p01;
    #pragma unroll
    for (int off = 1; off < 64; off <<= 1) {
        float v = __shfl_up(scan, off);
        if (lane >= off) scan *= v;
    }
    // Exclusive prefix for this lane = inclusive of lane-1.
    float excl = __shfl_up(scan, 1);
    if (lane == 0) excl = 1.0f;

    // P[2l] = excl*tr'[2l];  P[2l+1] = excl*tr'[2l]*tr'[2l+1]
    float w = a0 * (excl * tr0) + a1 * (excl * p01);

    // Wave sum reduction (butterfly).
    #pragma unroll
    for (int off = 32; off >= 1; off >>= 1)
        w += __shfl_xor(w, off);

    if (lane == 0)
        out[ray] = w;
}

extern "C" void kernel_launch(void* const* d_in, const int* in_sizes, int n_in,
                              void* d_out, int out_size, void* d_ws, size_t ws_size,
                              hipStream_t stream) {
    const float* t_stops = (const float*)d_in[0];
    const int*   leaves  = (const int*)d_in[1];
    const float* logits  = (const float*)d_in[2];
    float*       out     = (float*)d_out;

    // 4 rays per 256-thread block (one wave per ray).
    dim3 grid(NRAYS / 4), block(256);
    vc_kernel<<<grid, block, 0, stream>>>(t_stops, leaves, logits, out);
}

// Round 2
// 410.132 us; speedup vs baseline: 1.0348x; 1.0348x over previous
//
#include <hip/hip_runtime.h>
#include <math.h>

// VolumeCarver: out[r] = sum_i alpha_i * prod_{j=1..i} trans_j   (product includes j=i,
// excludes j=0), where alpha_i = 1-exp(-sigmoid(logits[leaf_i]) * delta_i),
// trans_j = min(1, 1-alpha_j+1e-10).
//
// Layout: one HALF-wave (32 lanes) per ray; lane owns 4 consecutive elements
// (float4/int4 loads, 16B/lane -> one wave covers exactly 2 contiguous ray rows).
// Reduction: associative pair (P, S): concat(A,B) = (P_A*P_B, S_A + P_A*S_B).
// 5 butterfly rounds (xor offsets 1..16 stay inside each half-wave).

#define NRAYS 262144
#define LEN   128
#define MAXD  1e10f
#define EPSW  1e-10f

__device__ __forceinline__ float fast_sigmoid(float x) {
    return __builtin_amdgcn_rcpf(1.0f + __expf(-x));
}

// 1 - exp(-x) for x >= 0. Small-x: 4-term poly (rel err < 1e-7 for x<0.1).
__device__ __forceinline__ float one_minus_exp_neg(float x) {
    float poly = x * (1.0f + x * (-0.5f + x * (0.16666667f - 0.041666668f * x)));
    float big  = 1.0f - __expf(-x);
    return (x < 0.1f) ? poly : big;
}

__global__ __launch_bounds__(256) void vc_kernel(
    const float* __restrict__ t_stops,   // [R, L]
    const int*   __restrict__ leaves,    // [R, L]
    const float* __restrict__ logits,    // [1M]
    float*       __restrict__ out)       // [R]
{
    const int lane = threadIdx.x & 63;
    const int wid  = blockIdx.x * 4 + (threadIdx.x >> 6);   // wave id
    const int ray  = wid * 2 + (lane >> 5);                  // 2 rays per wave
    const int sub  = lane & 31;                              // lane within ray

    const long long base = (long long)ray * LEN + sub * 4;

    float4 t4 = *(const float4*)(t_stops + base);
    int4   lv = *(const int4*)(leaves + base);

    // deltas; element 4*sub+3 needs next lane's t.x (MAXD at end of ray)
    float tnext = __shfl_down(t4.x, 1);
    float d0 = t4.y - t4.x;
    float d1 = t4.z - t4.y;
    float d2 = t4.w - t4.z;
    float d3 = (sub == 31) ? MAXD : (tnext - t4.w);

    // gather + sigmoid (fast)
    float x0 = fast_sigmoid(logits[lv.x]) * d0;
    float x1 = fast_sigmoid(logits[lv.y]) * d1;
    float x2 = fast_sigmoid(logits[lv.z]) * d2;
    float x3 = fast_sigmoid(logits[lv.w]) * d3;

    float a0 = one_minus_exp_neg(x0);
    float a1 = one_minus_exp_neg(x1);
    float a2 = one_minus_exp_neg(x2);
    float a3 = one_minus_exp_neg(x3);

    float tr0 = fminf(1.0f, 1.0f - a0 + EPSW);
    float tr1 = fminf(1.0f, 1.0f - a1 + EPSW);
    float tr2 = fminf(1.0f, 1.0f - a2 + EPSW);
    float tr3 = fminf(1.0f, 1.0f - a3 + EPSW);
    if (sub == 0) tr0 = 1.0f;   // trans[0] excluded from every product

    // local combine of 4 elements: S = sum a_e * (tr_0..tr_e), P = prod tr_e
    float c = tr0;
    float S = a0 * c;
    c *= tr1;  S = fmaf(a1, c, S);
    c *= tr2;  S = fmaf(a2, c, S);
    c *= tr3;  S = fmaf(a3, c, S);
    float P = c;

    // ordered butterfly reduction over the 32-lane half-wave
    #pragma unroll
    for (int o = 1; o < 32; o <<= 1) {
        float Pp = __shfl_xor(P, o);
        float Sp = __shfl_xor(S, o);
        // lower half of the 2o-block is the "earlier" segment
        S = (lane & o) ? fmaf(Pp, S, Sp) : fmaf(P, Sp, S);
        P *= Pp;
    }

    if (sub == 0)
        out[ray] = S;
}

extern "C" void kernel_launch(void* const* d_in, const int* in_sizes, int n_in,
                              void* d_out, int out_size, void* d_ws, size_t ws_size,
                              hipStream_t stream) {
    const float* t_stops = (const float*)d_in[0];
    const int*   leaves  = (const int*)d_in[1];
    const float* logits  = (const float*)d_in[2];
    float*       out     = (float*)d_out;

    // 8 rays per 256-thread block (2 rays per wave)
    dim3 grid(NRAYS / 8), block(256);
    vc_kernel<<<grid, block, 0, stream>>>(t_stops, leaves, logits, out);
}

// Round 3
// 371.640 us; speedup vs baseline: 1.1420x; 1.1036x over previous
//
#include <hip/hip_runtime.h>
#include <hip/hip_fp16.h>
#include <math.h>

// VolumeCarver: out[r] = sum_i alpha_i * prod_{j=1..i} trans_j  (includes j=i, excludes j=0)
// alpha_i = 1 - exp(-sigmoid(logits[leaf_i]) * delta_i); trans_j = min(1, 1-alpha_j+1e-10).
//
// R3: gather-path attack.
//  - Pre-pass builds fp16 sigmoid table (2MB, L2-resident) in d_ws -> gathers never miss L2.
//  - Wave = 4 rays x 16 lanes; 8 elements/lane in two 4-elem chunks -> 8 independent
//    gathers in flight per lane; all streaming loads 16B coalesced, nontemporal.
//  - (P,S) monoid butterfly over 16 lanes (4 rounds), then cross-chunk combine.

#define NRAYS 262144
#define LEN   128
#define NLEAF 1048576
#define MAXD  1e10f
#define EPSW  1e-10f

typedef float v4f __attribute__((ext_vector_type(4)));
typedef int   v4i __attribute__((ext_vector_type(4)));

__device__ __forceinline__ float fast_sigmoid(float x) {
    return __builtin_amdgcn_rcpf(1.0f + __expf(-x));
}

// 1 - exp(-x), x >= 0. Poly for small x (rel err < 2e-7 for x < 0.1).
__device__ __forceinline__ float omexp(float x) {
    float p = x * (1.0f + x * (-0.5f + x * (0.16666667f - 0.041666668f * x)));
    return (x < 0.1f) ? p : (1.0f - __expf(-x));
}

__global__ __launch_bounds__(256) void sig_kernel(const float* __restrict__ logits,
                                                  __half* __restrict__ tab) {
    int i = blockIdx.x * 256 + threadIdx.x;   // grid = NLEAF/256
    tab[i] = __float2half(fast_sigmoid(logits[i]));
}

template <bool TAB>
__global__ __launch_bounds__(256) void vc_kernel(
    const float* __restrict__ t_stops,   // [R, L]
    const int*   __restrict__ leaves,    // [R, L]
    const void*  __restrict__ table,     // __half sigmoid table (TAB) or raw f32 logits
    float*       __restrict__ out)       // [R]
{
    const int lane = threadIdx.x & 63;
    const int wid  = blockIdx.x * 4 + (threadIdx.x >> 6);
    const int ray  = wid * 4 + (lane >> 4);          // 4 rays per wave
    const int sub  = lane & 15;                      // 16 lanes per ray

    // chunk0 = elems [4*sub .. 4*sub+3], chunk1 = elems [64+4*sub .. 64+4*sub+3]
    const long long b0 = (long long)ray * LEN + sub * 4;
    const long long b1 = b0 + 64;

    v4i l0 = __builtin_nontemporal_load((const v4i*)(leaves + b0));
    v4i l1 = __builtin_nontemporal_load((const v4i*)(leaves + b1));
    v4f t0 = __builtin_nontemporal_load((const v4f*)(t_stops + b0));
    v4f t1 = __builtin_nontemporal_load((const v4f*)(t_stops + b1));

    // 8 independent gathers, all issued before any use.
    float op0, op1, op2, op3, op4, op5, op6, op7;
    if (TAB) {
        const __half* tb = (const __half*)table;
        op0 = __half2float(tb[l0.x]);  op1 = __half2float(tb[l0.y]);
        op2 = __half2float(tb[l0.z]);  op3 = __half2float(tb[l0.w]);
        op4 = __half2float(tb[l1.x]);  op5 = __half2float(tb[l1.y]);
        op6 = __half2float(tb[l1.z]);  op7 = __half2float(tb[l1.w]);
    } else {
        const float* lg = (const float*)table;
        op0 = fast_sigmoid(lg[l0.x]);  op1 = fast_sigmoid(lg[l0.y]);
        op2 = fast_sigmoid(lg[l0.z]);  op3 = fast_sigmoid(lg[l0.w]);
        op4 = fast_sigmoid(lg[l1.x]);  op5 = fast_sigmoid(lg[l1.y]);
        op6 = fast_sigmoid(lg[l1.z]);  op7 = fast_sigmoid(lg[l1.w]);
    }

    // deltas (overlaps gather latency; shfl is lgkm, gathers are vm)
    float tn0  = __shfl_down(t0.x, 1);               // next lane's chunk0 t.x
    float tn1  = __shfl_down(t1.x, 1);               // next lane's chunk1 t.x
    float tb1x = __shfl(t1.x, lane & 48);            // this ray-group's t[64]

    float d0a = t0.y - t0.x, d0b = t0.z - t0.y, d0c = t0.w - t0.z;
    float d0d = (sub == 15) ? (tb1x - t0.w) : (tn0 - t0.w);
    float d1a = t1.y - t1.x, d1b = t1.z - t1.y, d1c = t1.w - t1.z;
    float d1d = (sub == 15) ? MAXD : (tn1 - t1.w);

    float a0 = omexp(op0 * d0a), a1 = omexp(op1 * d0b);
    float a2 = omexp(op2 * d0c), a3 = omexp(op3 * d0d);
    float a4 = omexp(op4 * d1a), a5 = omexp(op5 * d1b);
    float a6 = omexp(op6 * d1c), a7 = omexp(op7 * d1d);

    float r0 = fminf(1.0f, 1.0f - a0 + EPSW), r1 = fminf(1.0f, 1.0f - a1 + EPSW);
    float r2 = fminf(1.0f, 1.0f - a2 + EPSW), r3 = fminf(1.0f, 1.0f - a3 + EPSW);
    float r4 = fminf(1.0f, 1.0f - a4 + EPSW), r5 = fminf(1.0f, 1.0f - a5 + EPSW);
    float r6 = fminf(1.0f, 1.0f - a6 + EPSW), r7 = fminf(1.0f, 1.0f - a7 + EPSW);
    if (sub == 0) r0 = 1.0f;                         // ray's trans[0] excluded everywhere

    // local (P,S) per chunk: S = sum a_e * prod(tr_0..tr_e), P = prod tr_e
    float c0 = r0;            float S0 = a0 * c0;
    c0 *= r1;                 S0 = fmaf(a1, c0, S0);
    c0 *= r2;                 S0 = fmaf(a2, c0, S0);
    c0 *= r3;                 S0 = fmaf(a3, c0, S0);
    float P0 = c0;
    float c1 = r4;            float S1 = a4 * c1;
    c1 *= r5;                 S1 = fmaf(a5, c1, S1);
    c1 *= r6;                 S1 = fmaf(a6, c1, S1);
    c1 *= r7;                 S1 = fmaf(a7, c1, S1);
    float P1 = c1;

    // ordered butterfly over the 16-lane ray group, both chunks at once
    #pragma unroll
    for (int o = 1; o < 16; o <<= 1) {
        float Pp0 = __shfl_xor(P0, o), Sp0 = __shfl_xor(S0, o);
        float Pp1 = __shfl_xor(P1, o), Sp1 = __shfl_xor(S1, o);
        if (lane & o) {   // partner is the earlier segment
            S0 = fmaf(Pp0, S0, Sp0);
            S1 = fmaf(Pp1, S1, Sp1);
        } else {          // partner is the later segment
            S0 = fmaf(P0, Sp0, S0);
            S1 = fmaf(P1, Sp1, S1);
        }
        P0 *= Pp0;
        P1 *= Pp1;
    }

    // ray = chunk0 ++ chunk1
    float S = fmaf(P0, S1, S0);
    if (sub == 0)
        out[ray] = S;
}

extern "C" void kernel_launch(void* const* d_in, const int* in_sizes, int n_in,
                              void* d_out, int out_size, void* d_ws, size_t ws_size,
                              hipStream_t stream) {
    const float* t_stops = (const float*)d_in[0];
    const int*   leaves  = (const int*)d_in[1];
    const float* logits  = (const float*)d_in[2];
    float*       out     = (float*)d_out;

    if (ws_size >= NLEAF * sizeof(__half)) {
        sig_kernel<<<NLEAF / 256, 256, 0, stream>>>(logits, (__half*)d_ws);
        // 16 rays per 256-thread block (4 rays per wave)
        vc_kernel<true><<<NRAYS / 16, 256, 0, stream>>>(t_stops, leaves, d_ws, out);
    } else {
        vc_kernel<false><<<NRAYS / 16, 256, 0, stream>>>(t_stops, leaves, logits, out);
    }
}

// Round 4
// 371.535 us; speedup vs baseline: 1.1423x; 1.0003x over previous
//
#include <hip/hip_runtime.h>
#include <hip/hip_fp16.h>
#include <math.h>

// VolumeCarver: out[r] = sum_i alpha_i * prod_{j=1..i} trans_j  (includes j=i, excludes j=0)
// alpha_i = 1 - exp(-sigmoid(logits[leaf_i]) * delta_i); trans_j = min(1, 1-alpha_j+1e-10).
//
// R4: R3 structure, but table gathers bypass L1 (agent-scope relaxed loads -> sc0,
// no 64B line allocation per random 2B gather). Theory: L2->L1 fill BW was the wall.

#define NRAYS 262144
#define LEN   128
#define NLEAF 1048576
#define MAXD  1e10f
#define EPSW  1e-10f

typedef float v4f __attribute__((ext_vector_type(4)));
typedef int   v4i __attribute__((ext_vector_type(4)));

__device__ __forceinline__ float fast_sigmoid(float x) {
    return __builtin_amdgcn_rcpf(1.0f + __expf(-x));
}

// 1 - exp(-x), x >= 0. Poly for small x (rel err < 2e-7 for x < 0.1).
__device__ __forceinline__ float omexp(float x) {
    float p = x * (1.0f + x * (-0.5f + x * (0.16666667f - 0.041666668f * x)));
    return (x < 0.1f) ? p : (1.0f - __expf(-x));
}

// L1-bypassing 2-byte gather from the sigmoid table (agent scope -> sc0, no L1 alloc).
__device__ __forceinline__ float tab_gather(const unsigned short* tb, int idx) {
    unsigned short u = __hip_atomic_load(tb + idx, __ATOMIC_RELAXED,
                                         __HIP_MEMORY_SCOPE_AGENT);
    __half h;
    *(unsigned short*)&h = u;
    return __half2float(h);
}

__global__ __launch_bounds__(256) void sig_kernel(const float* __restrict__ logits,
                                                  __half* __restrict__ tab) {
    int i = blockIdx.x * 256 + threadIdx.x;   // grid = NLEAF/256
    tab[i] = __float2half(fast_sigmoid(logits[i]));
}

template <bool TAB>
__global__ __launch_bounds__(256) void vc_kernel(
    const float* __restrict__ t_stops,   // [R, L]
    const int*   __restrict__ leaves,    // [R, L]
    const void*  __restrict__ table,     // __half sigmoid table (TAB) or raw f32 logits
    float*       __restrict__ out)       // [R]
{
    const int lane = threadIdx.x & 63;
    const int wid  = blockIdx.x * 4 + (threadIdx.x >> 6);
    const int ray  = wid * 4 + (lane >> 4);          // 4 rays per wave
    const int sub  = lane & 15;                      // 16 lanes per ray

    // chunk0 = elems [4*sub .. 4*sub+3], chunk1 = elems [64+4*sub .. 64+4*sub+3]
    const long long b0 = (long long)ray * LEN + sub * 4;
    const long long b1 = b0 + 64;

    v4i l0 = __builtin_nontemporal_load((const v4i*)(leaves + b0));
    v4i l1 = __builtin_nontemporal_load((const v4i*)(leaves + b1));
    v4f t0 = __builtin_nontemporal_load((const v4f*)(t_stops + b0));
    v4f t1 = __builtin_nontemporal_load((const v4f*)(t_stops + b1));

    // 8 independent gathers, all issued before any use.
    float op0, op1, op2, op3, op4, op5, op6, op7;
    if (TAB) {
        const unsigned short* tb = (const unsigned short*)table;
        op0 = tab_gather(tb, l0.x);  op1 = tab_gather(tb, l0.y);
        op2 = tab_gather(tb, l0.z);  op3 = tab_gather(tb, l0.w);
        op4 = tab_gather(tb, l1.x);  op5 = tab_gather(tb, l1.y);
        op6 = tab_gather(tb, l1.z);  op7 = tab_gather(tb, l1.w);
    } else {
        const float* lg = (const float*)table;
        op0 = fast_sigmoid(lg[l0.x]);  op1 = fast_sigmoid(lg[l0.y]);
        op2 = fast_sigmoid(lg[l0.z]);  op3 = fast_sigmoid(lg[l0.w]);
        op4 = fast_sigmoid(lg[l1.x]);  op5 = fast_sigmoid(lg[l1.y]);
        op6 = fast_sigmoid(lg[l1.z]);  op7 = fast_sigmoid(lg[l1.w]);
    }

    // deltas (overlaps gather latency)
    float tn0  = __shfl_down(t0.x, 1);               // next lane's chunk0 t.x
    float tn1  = __shfl_down(t1.x, 1);               // next lane's chunk1 t.x
    float tb1x = __shfl(t1.x, lane & 48);            // this ray-group's t[64]

    float d0a = t0.y - t0.x, d0b = t0.z - t0.y, d0c = t0.w - t0.z;
    float d0d = (sub == 15) ? (tb1x - t0.w) : (tn0 - t0.w);
    float d1a = t1.y - t1.x, d1b = t1.z - t1.y, d1c = t1.w - t1.z;
    float d1d = (sub == 15) ? MAXD : (tn1 - t1.w);

    float a0 = omexp(op0 * d0a), a1 = omexp(op1 * d0b);
    float a2 = omexp(op2 * d0c), a3 = omexp(op3 * d0d);
    float a4 = omexp(op4 * d1a), a5 = omexp(op5 * d1b);
    float a6 = omexp(op6 * d1c), a7 = omexp(op7 * d1d);

    float r0 = fminf(1.0f, 1.0f - a0 + EPSW), r1 = fminf(1.0f, 1.0f - a1 + EPSW);
    float r2 = fminf(1.0f, 1.0f - a2 + EPSW), r3 = fminf(1.0f, 1.0f - a3 + EPSW);
    float r4 = fminf(1.0f, 1.0f - a4 + EPSW), r5 = fminf(1.0f, 1.0f - a5 + EPSW);
    float r6 = fminf(1.0f, 1.0f - a6 + EPSW), r7 = fminf(1.0f, 1.0f - a7 + EPSW);
    if (sub == 0) r0 = 1.0f;                         // ray's trans[0] excluded everywhere

    // local (P,S) per chunk: S = sum a_e * prod(tr_0..tr_e), P = prod tr_e
    float c0 = r0;            float S0 = a0 * c0;
    c0 *= r1;                 S0 = fmaf(a1, c0, S0);
    c0 *= r2;                 S0 = fmaf(a2, c0, S0);
    c0 *= r3;                 S0 = fmaf(a3, c0, S0);
    float P0 = c0;
    float c1 = r4;            float S1 = a4 * c1;
    c1 *= r5;                 S1 = fmaf(a5, c1, S1);
    c1 *= r6;                 S1 = fmaf(a6, c1, S1);
    c1 *= r7;                 S1 = fmaf(a7, c1, S1);
    float P1 = c1;

    // ordered butterfly over the 16-lane ray group, both chunks at once
    #pragma unroll
    for (int o = 1; o < 16; o <<= 1) {
        float Pp0 = __shfl_xor(P0, o), Sp0 = __shfl_xor(S0, o);
        float Pp1 = __shfl_xor(P1, o), Sp1 = __shfl_xor(S1, o);
        if (lane & o) {   // partner is the earlier segment
            S0 = fmaf(Pp0, S0, Sp0);
            S1 = fmaf(Pp1, S1, Sp1);
        } else {          // partner is the later segment
            S0 = fmaf(P0, Sp0, S0);
            S1 = fmaf(P1, Sp1, S1);
        }
        P0 *= Pp0;
        P1 *= Pp1;
    }

    // ray = chunk0 ++ chunk1
    float S = fmaf(P0, S1, S0);
    if (sub == 0)
        out[ray] = S;
}

extern "C" void kernel_launch(void* const* d_in, const int* in_sizes, int n_in,
                              void* d_out, int out_size, void* d_ws, size_t ws_size,
                              hipStream_t stream) {
    const float* t_stops = (const float*)d_in[0];
    const int*   leaves  = (const int*)d_in[1];
    const float* logits  = (const float*)d_in[2];
    float*       out     = (float*)d_out;

    if (ws_size >= NLEAF * sizeof(__half)) {
        sig_kernel<<<NLEAF / 256, 256, 0, stream>>>(logits, (__half*)d_ws);
        // 16 rays per 256-thread block (4 rays per wave)
        vc_kernel<true><<<NRAYS / 16, 256, 0, stream>>>(t_stops, leaves, d_ws, out);
    } else {
        vc_kernel<false><<<NRAYS / 16, 256, 0, stream>>>(t_stops, leaves, logits, out);
    }
}

// Round 5
// 365.285 us; speedup vs baseline: 1.1618x; 1.0171x over previous
//
#include <hip/hip_runtime.h>
#include <hip/hip_fp16.h>
#include <math.h>

// VolumeCarver: out[r] = sum_i alpha_i * prod_{j=1..i} trans_j  (includes j=i, excludes j=0)
// alpha_i = 1 - exp(-sigmoid(logits[leaf_i]) * delta_i); trans_j = min(1, 1-alpha_j+1e-10).
//
// R5: (1) dword-aligned gathers from the fp16 sigmoid table (no sub-dword loads),
//     (2) wave = 8 rays x 8 lanes, 16 elements/lane in 4 chunks -> 16 gathers in
//     flight per lane (2x MLP of R4), butterfly reduced to 3 rounds.

#define NRAYS 262144
#define LEN   128
#define NLEAF 1048576
#define MAXD  1e10f
#define EPSW  1e-10f

typedef float v4f __attribute__((ext_vector_type(4)));
typedef int   v4i __attribute__((ext_vector_type(4)));

__device__ __forceinline__ float fast_sigmoid(float x) {
    return __builtin_amdgcn_rcpf(1.0f + __expf(-x));
}

// 1 - exp(-x), x >= 0. Poly for small x (rel err < 2e-7 for x < 0.1).
__device__ __forceinline__ float omexp(float x) {
    float p = x * (1.0f + x * (-0.5f + x * (0.16666667f - 0.041666668f * x)));
    return (x < 0.1f) ? p : (1.0f - __expf(-x));
}

// Dword-aligned gather of fp16 entry idx from table (2B entries packed in dwords).
__device__ __forceinline__ float tab_gather32(const unsigned int* tb32, int idx) {
    unsigned int v = tb32[idx >> 1];
    unsigned short u = (unsigned short)(v >> ((idx & 1) * 16));
    __half h;
    *(unsigned short*)&h = u;
    return __half2float(h);
}

__global__ __launch_bounds__(256) void sig_kernel(const float* __restrict__ logits,
                                                  __half* __restrict__ tab) {
    int i = blockIdx.x * 256 + threadIdx.x;   // grid = NLEAF/256
    tab[i] = __float2half(fast_sigmoid(logits[i]));
}

template <bool TAB>
__global__ __launch_bounds__(256) void vc_kernel(
    const float* __restrict__ t_stops,   // [R, L]
    const int*   __restrict__ leaves,    // [R, L]
    const void*  __restrict__ table,     // fp16 sigmoid table (TAB) or raw f32 logits
    float*       __restrict__ out)       // [R]
{
    const int lane = threadIdx.x & 63;
    const int wid  = blockIdx.x * 4 + (threadIdx.x >> 6);
    const int ray  = wid * 8 + (lane >> 3);          // 8 rays per wave
    const int sub  = lane & 7;                       // 8 lanes per ray
    const int gbase = lane & 56;                     // first lane of this ray group

    // chunk c covers elements [c*32 + sub*4 .. +3] of the ray (c = 0..3)
    const long long rb = (long long)ray * LEN + sub * 4;

    v4i lv[4];
    v4f tt[4];
    #pragma unroll
    for (int c = 0; c < 4; ++c)
        lv[c] = __builtin_nontemporal_load((const v4i*)(leaves + rb + c * 32));
    #pragma unroll
    for (int c = 0; c < 4; ++c)
        tt[c] = __builtin_nontemporal_load((const v4f*)(t_stops + rb + c * 32));

    // 16 independent gathers issued back-to-back.
    float op[4][4];
    if (TAB) {
        const unsigned int* tb32 = (const unsigned int*)table;
        #pragma unroll
        for (int c = 0; c < 4; ++c) {
            op[c][0] = tab_gather32(tb32, lv[c].x);
            op[c][1] = tab_gather32(tb32, lv[c].y);
            op[c][2] = tab_gather32(tb32, lv[c].z);
            op[c][3] = tab_gather32(tb32, lv[c].w);
        }
    } else {
        const float* lg = (const float*)table;
        #pragma unroll
        for (int c = 0; c < 4; ++c) {
            op[c][0] = fast_sigmoid(lg[lv[c].x]);
            op[c][1] = fast_sigmoid(lg[lv[c].y]);
            op[c][2] = fast_sigmoid(lg[lv[c].z]);
            op[c][3] = fast_sigmoid(lg[lv[c].w]);
        }
    }

    // Per-chunk local (P,S) over the lane's 4 consecutive elements.
    float P[4], S[4];
    #pragma unroll
    for (int c = 0; c < 4; ++c) {
        // value of the element AFTER this lane's last one in chunk c:
        //   sub<7 : next lane's tt[c].x
        //   sub==7: chunk c+1's tt.x at group's lane 0 (or MAXD at ray end)
        float nxt_dn = __shfl_down(tt[c].x, 1);
        float nxt_c1 = (c < 3) ? __shfl(tt[(c + 1) & 3].x, gbase) : MAXD;
        float nxt = (sub == 7) ? nxt_c1 : nxt_dn;

        float d0 = tt[c].y - tt[c].x;
        float d1 = tt[c].z - tt[c].y;
        float d2 = tt[c].w - tt[c].z;
        float d3 = nxt - tt[c].w;

        float a0 = omexp(op[c][0] * d0);
        float a1 = omexp(op[c][1] * d1);
        float a2 = omexp(op[c][2] * d2);
        float a3 = omexp(op[c][3] * d3);

        float r0 = fminf(1.0f, 1.0f - a0 + EPSW);
        float r1 = fminf(1.0f, 1.0f - a1 + EPSW);
        float r2 = fminf(1.0f, 1.0f - a2 + EPSW);
        float r3 = fminf(1.0f, 1.0f - a3 + EPSW);
        if (c == 0 && sub == 0) r0 = 1.0f;   // ray's trans[0] excluded everywhere

        float cc = r0;        float ss = a0 * cc;
        cc *= r1;             ss = fmaf(a1, cc, ss);
        cc *= r2;             ss = fmaf(a2, cc, ss);
        cc *= r3;             ss = fmaf(a3, cc, ss);
        P[c] = cc;  S[c] = ss;
    }

    // Ordered butterfly over the 8-lane ray group, all 4 chunks concurrently.
    #pragma unroll
    for (int o = 1; o < 8; o <<= 1) {
        #pragma unroll
        for (int c = 0; c < 4; ++c) {
            float Pp = __shfl_xor(P[c], o);
            float Sp = __shfl_xor(S[c], o);
            S[c] = (lane & o) ? fmaf(Pp, S[c], Sp) : fmaf(P[c], Sp, S[c]);
            P[c] *= Pp;
        }
    }

    // Chain the 4 chunk segments in order.
    float Sr = fmaf(P[2], S[3], S[2]);
    Sr = fmaf(P[1], Sr, S[1]);
    Sr = fmaf(P[0], Sr, S[0]);

    if (sub == 0)
        out[ray] = Sr;
}

extern "C" void kernel_launch(void* const* d_in, const int* in_sizes, int n_in,
                              void* d_out, int out_size, void* d_ws, size_t ws_size,
                              hipStream_t stream) {
    const float* t_stops = (const float*)d_in[0];
    const int*   leaves  = (const int*)d_in[1];
    const float* logits  = (const float*)d_in[2];
    float*       out     = (float*)d_out;

    if (ws_size >= NLEAF * sizeof(__half)) {
        sig_kernel<<<NLEAF / 256, 256, 0, stream>>>(logits, (__half*)d_ws);
        // 32 rays per 256-thread block (8 rays per wave)
        vc_kernel<true><<<NRAYS / 32, 256, 0, stream>>>(t_stops, leaves, d_ws, out);
    } else {
        vc_kernel<false><<<NRAYS / 32, 256, 0, stream>>>(t_stops, leaves, logits, out);
    }
}